// Round 3
// baseline (1807.178 us; speedup 1.0000x reference)
//
#include <hip/hip_runtime.h>
#include <cstdint>
#include <cstddef>

#define IMPOSSIBLE -10000.0f

constexpr int B = 64;
constexpr int T = 2048;
constexpr int N = 128;

// One block per chain (channel c in {0 sup,1 full} x batch b). 256 threads:
//   j = tid & 127  (output state), h = tid >> 7 (half of the i/summation dim).
// E[i][j] column slice (64 floats) lives in registers per thread.
// Per step: p_i = exp(alpha_i - M) broadcast via LDS; s_j = sum p_i E_ij ;
// alpha_j = M + log(s_j) + em_j ; M = block max(alpha) via shfl+LDS.
// NOTE: bool inputs arrive as int32 (harness ABI: "integer -> const int*").
// Epilogue: z written to z_ws[chain] (plain store). No atomics, no d_out RMW,
// no memset -- kernel_launch is a pure function of d_in (determinism tripwire).
__global__ __launch_bounds__(256, 1) void crf_chain_kernel(
    const float* __restrict__ emissions,    // [B,T,N] f32
    const int* __restrict__ mask,           // [B,T] int32 (bool)
    const int* __restrict__ target,         // [B,T,N] int32 (bool)
    const float* __restrict__ transitions,  // [N,N]
    const float* __restrict__ start_tr,     // [N]
    const float* __restrict__ end_tr,       // [N]
    const int* __restrict__ forb,           // [N,N] int32 (bool)
    const int* __restrict__ start_forb,     // [N] int32 (bool)
    const int* __restrict__ end_forb,       // [N] int32 (bool)
    float* __restrict__ z_ws)               // [128] workspace
{
    const int chain = blockIdx.x;  // 0..127
    const int c = chain >> 6;      // 0 = supervised (target-clamped), 1 = full
    const int b = chain & 63;
    const int tid = (int)threadIdx.x;
    const int j = tid & 127;
    const int h = tid >> 7;
    const int wave = tid >> 6;
    const int lane = tid & 63;

    __shared__ float p_lds[128];
    __shared__ float spart[256];
    __shared__ float wm[4];
    __shared__ int lred[4];

    // ---- sequence length from mask ----
    int lsum = 0;
    for (int k = tid; k < T; k += 256) lsum += (mask[b * T + k] != 0);
    #pragma unroll
    for (int d = 1; d < 64; d <<= 1) lsum += __shfl_xor(lsum, d);
    if (lane == 0) lred[wave] = lsum;
    __syncthreads();
    const int tlast = (lred[0] + lred[1] + lred[2] + lred[3]) - 1;

    // ---- E column slice -> registers: e[k] = E[64h+k][j] ----
    float e[64];
    #pragma unroll
    for (int k = 0; k < 64; ++k) {
        const int i = h * 64 + k;
        const float tv = transitions[i * N + j];
        e[k] = forb[i * N + j] ? 0.0f : __expf(tv);
    }

    const float* embase = emissions + (size_t)b * T * N;
    const int* tgbase = target + (size_t)b * T * N;

    // ---- alpha at t=0 ----
    float st = start_forb[j] ? IMPOSSIBLE : start_tr[j];
    float em0 = embase[j];
    if (c == 0 && !tgbase[j]) em0 = IMPOSSIBLE;
    float alpha = em0 + st;
    float saved = alpha;  // covers tlast == 0

    // initial block max of alpha
    float wmax = alpha;
    #pragma unroll
    for (int d = 1; d < 64; d <<= 1) wmax = fmaxf(wmax, __shfl_xor(wmax, d));
    if (lane == 0) wm[wave] = wmax;
    __syncthreads();
    float M = fmaxf(fmaxf(fmaxf(wm[0], wm[1]), fmaxf(wm[2], wm[3])), -1e30f);

    // prefetch t = 1
    float em_n = embase[N + j];
    int tg_n = (c == 0) ? tgbase[N + j] : 1;

    for (int t = 1; t < T; ++t) {
        const float em_c = em_n;
        const int tg_c = tg_n;
        if (t + 1 < T) {
            em_n = embase[(size_t)(t + 1) * N + j];
            if (c == 0) tg_n = tgbase[(size_t)(t + 1) * N + j];
        }

        // p broadcast
        const float pj = __expf(alpha - M);
        if (h == 0) p_lds[j] = pj;
        __syncthreads();

        // s_j partial over this thread's 64 i's
        float s = 0.0f;
        const float4* p4 = reinterpret_cast<const float4*>(&p_lds[h * 64]);
        #pragma unroll
        for (int k = 0; k < 16; ++k) {
            const float4 pv = p4[k];
            s = fmaf(pv.x, e[4 * k + 0], s);
            s = fmaf(pv.y, e[4 * k + 1], s);
            s = fmaf(pv.z, e[4 * k + 2], s);
            s = fmaf(pv.w, e[4 * k + 3], s);
        }
        spart[h * 128 + j] = s;
        __syncthreads();
        const float stot = spart[j] + spart[128 + j];

        float em = (c == 0 && !tg_c) ? IMPOSSIBLE : em_c;
        const float lg = (stot > 0.0f) ? __logf(stot) : -1e30f;
        alpha = M + lg + em;
        if (t == tlast) saved = alpha;

        // block max for next step
        wmax = alpha;
        #pragma unroll
        for (int d = 1; d < 64; d <<= 1) wmax = fmaxf(wmax, __shfl_xor(wmax, d));
        if (lane == 0) wm[wave] = wmax;
        __syncthreads();
        M = fmaxf(fmaxf(fmaxf(wm[0], wm[1]), fmaxf(wm[2], wm[3])), -1e30f);
    }

    // ---- z = logsumexp_j(saved + en_j) ----
    const float en = end_forb[j] ? IMPOSSIBLE : end_tr[j];
    const float v = saved + en;

    float m2 = v;
    #pragma unroll
    for (int d = 1; d < 64; d <<= 1) m2 = fmaxf(m2, __shfl_xor(m2, d));
    if (lane == 0) wm[wave] = m2;
    __syncthreads();
    m2 = fmaxf(fmaxf(fmaxf(wm[0], wm[1]), fmaxf(wm[2], wm[3])), -1e30f);

    float se = __expf(v - m2);
    #pragma unroll
    for (int d = 1; d < 64; d <<= 1) se += __shfl_xor(se, d);
    if (lane == 0) spart[wave] = se;
    __syncthreads();
    // waves 0 and 1 (h==0) cover j = 0..127 exactly once
    const float ssum = spart[0] + spart[1];
    const float z = m2 + __logf(ssum);

    if (tid == 0) z_ws[chain] = z;
}

// out[b] = z_full[b] - z_sup[b]; plain stores, overwrites every element.
__global__ void crf_combine_kernel(const float* __restrict__ z_ws,
                                   float* __restrict__ out) {
    const int b = (int)threadIdx.x;
    if (b < B) out[b] = z_ws[B + b] - z_ws[b];
}

extern "C" void kernel_launch(void* const* d_in, const int* in_sizes, int n_in,
                              void* d_out, int out_size, void* d_ws, size_t ws_size,
                              hipStream_t stream) {
    const float* emissions = (const float*)d_in[0];
    const int* mask = (const int*)d_in[1];
    const int* target = (const int*)d_in[2];
    const float* transitions = (const float*)d_in[3];
    const float* start_tr = (const float*)d_in[4];
    const float* end_tr = (const float*)d_in[5];
    const int* forb = (const int*)d_in[6];
    const int* start_forb = (const int*)d_in[7];
    const int* end_forb = (const int*)d_in[8];
    float* out = (float*)d_out;
    float* z_ws = (float*)d_ws;

    crf_chain_kernel<<<dim3(2 * B), dim3(256), 0, stream>>>(
        emissions, mask, target, transitions, start_tr, end_tr,
        forb, start_forb, end_forb, z_ws);
    crf_combine_kernel<<<dim3(1), dim3(64), 0, stream>>>(z_ws, out);
}

// Round 4
// 1455.764 us; speedup vs baseline: 1.2414x; 1.2414x over previous
//
#include <hip/hip_runtime.h>
#include <cstdint>
#include <cstddef>

#define IMPOSSIBLE -10000.0f
#define INV_LN2 1.44269504088896340736f
#define LN2 0.69314718055994530942f
#define IMP2 (IMPOSSIBLE * INV_LN2)

constexpr int B = 64;
constexpr int T = 2048;
constexpr int N = 128;

// One block per chain (c,b). 256 threads, 4 waves.
// j = 32*wave + (lane&31); h = lane>>5 selects the i-half [64h,64h+64).
// Per step (ONE raw barrier, no vmcnt drain):
//   matvec from p_buf[prv] (broadcast float4 LDS reads, 4 accumulators)
//   stot = s + shfl_xor(s,32)   (both halves in same wave)
//   a2 = m2 + log2(stot) + em2  (log2 domain; em prescaled at prefetch)
//   m2 += log2(slot[prv])       (anchored stale-max; uniform, off-path)
//   p_buf[cur][j] = exp2(a2-m2) (h=0 lanes only); thread j=0 writes slot[cur]=stot
// Bool inputs arrive as int32. Output via z_ws (pure function of d_in).
__global__ __launch_bounds__(256, 1) void crf_chain_kernel(
    const float* __restrict__ emissions,    // [B,T,N] f32
    const int* __restrict__ mask,           // [B,T]
    const int* __restrict__ target,         // [B,T,N]
    const float* __restrict__ transitions,  // [N,N]
    const float* __restrict__ start_tr,     // [N]
    const float* __restrict__ end_tr,       // [N]
    const int* __restrict__ forb,           // [N,N]
    const int* __restrict__ start_forb,     // [N]
    const int* __restrict__ end_forb,       // [N]
    float* __restrict__ z_ws)               // [128]
{
    const int chain = blockIdx.x;  // 0..127
    const int c = chain >> 6;      // 0 = supervised, 1 = full
    const int b = chain & 63;
    const int tid = (int)threadIdx.x;
    const int wave = tid >> 6;
    const int lane = tid & 63;
    const int h = lane >> 5;               // i-half
    const int j = (wave << 5) | (lane & 31);

    __shared__ __align__(16) float p_buf[2][128];
    __shared__ float slot[2];
    __shared__ float wred[4];
    __shared__ int lred[4];

    // ---- sequence length ----
    int lsum = 0;
    for (int k = tid; k < T; k += 256) lsum += (mask[b * T + k] != 0);
    #pragma unroll
    for (int d = 1; d < 64; d <<= 1) lsum += __shfl_xor(lsum, d);
    if (lane == 0) lred[wave] = lsum;
    __syncthreads();
    const int tlast = (lred[0] + lred[1] + lred[2] + lred[3]) - 1;

    // ---- E column slice: e[k] = exp(trans[64h+k][j]) or 0 ----
    float e[64];
    #pragma unroll
    for (int k = 0; k < 64; ++k) {
        const int i = (h << 6) + k;
        const float tv = transitions[i * N + j];
        e[k] = forb[i * N + j] ? 0.0f : __expf(tv);
    }

    const float* embase = emissions + (size_t)b * T * N;
    const int* tgbase = target + (size_t)b * T * N;

    // ---- t = 0 ----
    const float st = start_forb[j] ? IMPOSSIBLE : start_tr[j];
    float em0 = embase[j];
    if (c == 0 && !tgbase[j]) em0 = IMPOSSIBLE;
    float a2 = (em0 + st) * INV_LN2;   // log2-domain alpha
    float saved2 = a2;

    // exact initial max (init only)
    float wmax = a2;
    #pragma unroll
    for (int d = 1; d < 64; d <<= 1) wmax = fmaxf(wmax, __shfl_xor(wmax, d));
    if (lane == 0) wred[wave] = wmax;
    __syncthreads();
    float m2 = fmaxf(fmaxf(wred[0], wred[1]), fmaxf(wred[2], wred[3]));

    if ((lane & 32) == 0) {
        p_buf[0][j] = exp2f(a2 - m2);
        if (tid == 0) { slot[0] = 1.0f; slot[1] = 1.0f; }
    }

    // ---- emission prefetch, depth 2, prescaled ----
    float emA = embase[(size_t)1 * N + j];
    int tgA = (c == 0) ? tgbase[(size_t)1 * N + j] : 1;
    float emB = embase[(size_t)2 * N + j];
    int tgB = (c == 0) ? tgbase[(size_t)2 * N + j] : 1;
    float effA = tgA ? emA * INV_LN2 : IMP2;   // em2 for t=1

    #pragma unroll 2
    for (int t = 1; t < T; ++t) {
        // raw barrier: LDS drained, global loads stay in flight
        asm volatile("s_waitcnt lgkmcnt(0)\n\ts_barrier" ::: "memory");

        const int cur = t & 1, prv = cur ^ 1;
        const float slotv = slot[prv];

        // matvec: s_j(half h) = sum_k p[64h+k] * e[k]
        const float4* p4 = reinterpret_cast<const float4*>(&p_buf[prv][h << 6]);
        float a0 = 0.0f, a1 = 0.0f, a2c = 0.0f, a3 = 0.0f;
        #pragma unroll
        for (int k = 0; k < 16; k += 4) {
            const float4 v0 = p4[k], v1 = p4[k + 1], v2 = p4[k + 2], v3 = p4[k + 3];
            a0 = fmaf(v0.x, e[4*k+0], a0);  a0 = fmaf(v0.y, e[4*k+1], a0);
            a0 = fmaf(v0.z, e[4*k+2], a0);  a0 = fmaf(v0.w, e[4*k+3], a0);
            a1 = fmaf(v1.x, e[4*k+4], a1);  a1 = fmaf(v1.y, e[4*k+5], a1);
            a1 = fmaf(v1.z, e[4*k+6], a1);  a1 = fmaf(v1.w, e[4*k+7], a1);
            a2c = fmaf(v2.x, e[4*k+8], a2c);  a2c = fmaf(v2.y, e[4*k+9], a2c);
            a2c = fmaf(v2.z, e[4*k+10], a2c); a2c = fmaf(v2.w, e[4*k+11], a2c);
            a3 = fmaf(v3.x, e[4*k+12], a3);  a3 = fmaf(v3.y, e[4*k+13], a3);
            a3 = fmaf(v3.z, e[4*k+14], a3);  a3 = fmaf(v3.w, e[4*k+15], a3);
        }
        const float s = (a0 + a1) + (a2c + a3);
        const float stot = s + __shfl_xor(s, 32);

        // prefetch t+2 (covered by ~2 steps of latency; no barrier drains it)
        float em_new = 0.0f; int tg_new = 1;
        if (t + 2 < T) {
            em_new = embase[(size_t)(t + 2) * N + j];
            if (c == 0) tg_new = tgbase[(size_t)(t + 2) * N + j];
        }

        // anchored stale-max update (uniform across all threads, off-path)
        const float m2n = m2 + __log2f(fmaxf(slotv, 1e-30f));

        a2 = m2 + __log2f(stot) + effA;   // m2 = scale of p[prv]
        if (t == tlast) saved2 = a2;
        m2 = m2n;                          // scale for p[cur]

        if ((lane & 32) == 0) {
            p_buf[cur][j] = exp2f(a2 - m2);
            if (tid == 0) slot[cur] = stot;
        }

        // rotate emission pipeline
        effA = tgB ? emB * INV_LN2 : IMP2;
        emB = em_new; tgB = tg_new;
    }

    // ---- z = logsumexp_j(saved + en_j); j duplicated x2 across h ----
    const float en = end_forb[j] ? IMPOSSIBLE : end_tr[j];
    const float v = saved2 * LN2 + en;

    float m3 = v;
    #pragma unroll
    for (int d = 1; d < 64; d <<= 1) m3 = fmaxf(m3, __shfl_xor(m3, d));
    if (lane == 0) wred[wave] = m3;
    __syncthreads();
    m3 = fmaxf(fmaxf(wred[0], wred[1]), fmaxf(wred[2], wred[3]));

    float se = __expf(v - m3);
    #pragma unroll
    for (int d = 1; d < 64; d <<= 1) se += __shfl_xor(se, d);
    __syncthreads();               // reuse wred safely
    if (lane == 0) wred[wave] = se;
    __syncthreads();
    const float tot = (wred[0] + wred[1]) + (wred[2] + wred[3]);  // = 2 * sum
    const float z = m3 + __logf(tot * 0.5f);

    if (tid == 0) z_ws[chain] = z;
}

__global__ void crf_combine_kernel(const float* __restrict__ z_ws,
                                   float* __restrict__ out) {
    const int b = (int)threadIdx.x;
    if (b < B) out[b] = z_ws[B + b] - z_ws[b];
}

extern "C" void kernel_launch(void* const* d_in, const int* in_sizes, int n_in,
                              void* d_out, int out_size, void* d_ws, size_t ws_size,
                              hipStream_t stream) {
    const float* emissions = (const float*)d_in[0];
    const int* mask = (const int*)d_in[1];
    const int* target = (const int*)d_in[2];
    const float* transitions = (const float*)d_in[3];
    const float* start_tr = (const float*)d_in[4];
    const float* end_tr = (const float*)d_in[5];
    const int* forb = (const int*)d_in[6];
    const int* start_forb = (const int*)d_in[7];
    const int* end_forb = (const int*)d_in[8];
    float* out = (float*)d_out;
    float* z_ws = (float*)d_ws;

    crf_chain_kernel<<<dim3(2 * B), dim3(256), 0, stream>>>(
        emissions, mask, target, transitions, start_tr, end_tr,
        forb, start_forb, end_forb, z_ws);
    crf_combine_kernel<<<dim3(1), dim3(64), 0, stream>>>(z_ws, out);
}